// Round 16
// baseline (316.454 us; speedup 1.0000x reference)
//
#include <hip/hip_runtime.h>

#define N_NODES 100000
#define N_EDGES 1600000
#define TOT (N_EDGES + N_NODES)
#define IN_CH 256
#define NHEAD 4
#define CH 64
#define HC 256
#define NEG_SLOPE 0.2f
#define NGEMM ((N_NODES + 63) / 64)  // 1563 gemm blocks
#define DEG_BLOCKS 391               // 391*256*4 int4 >= 400,000

typedef _Float16 half8 __attribute__((ext_vector_type(8)));
typedef _Float16 h2v __attribute__((ext_vector_type(2)));
typedef float f32x4 __attribute__((ext_vector_type(4)));
typedef unsigned short ushort_t;
typedef unsigned int uint_t;

static __device__ __forceinline__ ushort_t f2h(float f) {
  _Float16 h = (_Float16)f;
  return __builtin_bit_cast(ushort_t, h);
}

// async global->LDS, 16B per lane (dest = wave-uniform base + lane*16)
static __device__ __forceinline__ void gload_lds16(const char* g, char* l) {
  __builtin_amdgcn_global_load_lds(
      (const __attribute__((address_space(1))) unsigned int*)g,
      (__attribute__((address_space(3))) unsigned int*)l, 16, 0, 0);
}

// ---------------- W fp32 [K=256][N=256] -> Wt_arr, MFMA-fragment-major ----------------
__global__ __launch_bounds__(256) void conv_w(const float* __restrict__ W,
                                              uint4* __restrict__ Wt_arr) {
  int id = blockIdx.x * 256 + threadIdx.x;  // 0..8191
  int lane = id & 63;
  int n = (id >> 6) & 15;
  int ks = id >> 10;
  int col = n * 16 + (lane & 15);
  int kbase = ks * 32 + (lane >> 4) * 8;
  ushort_t h[8];
#pragma unroll
  for (int j = 0; j < 8; ++j) h[j] = f2h(W[(size_t)(kbase + j) * HC + col]);
  uint4 u;
  u.x = (uint_t)h[0] | ((uint_t)h[1] << 16);
  u.y = (uint_t)h[2] | ((uint_t)h[3] << 16);
  u.z = (uint_t)h[4] | ((uint_t)h[5] << 16);
  u.w = (uint_t)h[6] | ((uint_t)h[7] << 16);
  Wt_arr[id] = u;
}

// ---------------- grid-mix: GEMM blocks FIRST, deg-count blocks LAST ----------------
// GEMM: triple-buffered LDS staging, raw s_barrier + counted vmcnt (T3/T4).
__global__ __launch_bounds__(256) void gemm_mfma(const float* __restrict__ X,
                                                 const uint4* __restrict__ Wt_arr,
                                                 const float* __restrict__ att_src,
                                                 const float* __restrict__ att_dst,
                                                 uint2* __restrict__ Hmp,
                                                 float* __restrict__ as_out,
                                                 float* __restrict__ ad_out,
                                                 const int* __restrict__ edst,
                                                 int* __restrict__ deg, int M) {
  const int tid = threadIdx.x;

  if (blockIdx.x >= NGEMM) {  // deg blocks: dispatched LAST, backfill gemm's tail
    int db = blockIdx.x - NGEMM;
#pragma unroll
    for (int i = 0; i < 4; ++i) {
      int t = (db * 4 + i) * 256 + tid;
      if (t < N_EDGES / 4) {
        int4 d4 = reinterpret_cast<const int4*>(edst)[t];
        atomicAdd(&deg[d4.x], 1);
        atomicAdd(&deg[d4.y], 1);
        atomicAdd(&deg[d4.z], 1);
        atomicAdd(&deg[d4.w], 1);
      }
    }
    return;
  }

  __shared__ uint4 Bs[3][1024];                // 3 x 16 KB
  __shared__ __align__(16) float As[3][2048];  // 3 x 8 KB (64 rows x 32 f32)
  const int lane = tid & 63;
  const int wid = tid >> 6;
  const int l16 = lane & 15;
  const int lhi = lane >> 4;
  const int row0 = blockIdx.x * 64;

  const int arow = tid >> 3;
  const int aslot = tid & 7;
  int ga0 = row0 + arow;       if (ga0 >= M) ga0 = M - 1;
  int ga1 = row0 + arow + 32;  if (ga1 >= M) ga1 = M - 1;
  const int sslot = aslot ^ (arow & 7);
  const char* asrc0 = (const char*)X + (size_t)ga0 * 1024 + (sslot << 4);
  const char* asrc1 = (const char*)X + (size_t)ga1 * 1024 + (sslot << 4);

  const char* __restrict__ wsrc = (const char*)Wt_arr;

  const int frow = wid * 16 + l16;
  const int sw = frow & 7;
  const int fo0 = frow * 32 + (((2 * lhi + 0) ^ sw) << 2);
  const int fo1 = frow * 32 + (((2 * lhi + 1) ^ sw) << 2);

  auto ISSUE = [&](int kk, int b) {
    char* ad = (char*)&As[b][0] + tid * 16;
    gload_lds16(asrc0 + kk * 128, ad);
    gload_lds16(asrc1 + kk * 128, ad + 4096);
    char* bd = (char*)&Bs[b][0] + tid * 16;
    const char* s = wsrc + kk * 16384 + tid * 16;
    gload_lds16(s,         bd);
    gload_lds16(s + 4096,  bd + 4096);
    gload_lds16(s + 8192,  bd + 8192);
    gload_lds16(s + 12288, bd + 12288);
  };

  ISSUE(0, 0);
  ISSUE(1, 1);

  f32x4 acc[16] = {};

#pragma unroll
  for (int ks = 0; ks < 8; ++ks) {
    __builtin_amdgcn_s_barrier();
    if (ks < 6) ISSUE(ks + 2, (ks + 2) % 3);
    if (ks < 6)       asm volatile("s_waitcnt vmcnt(12)" ::: "memory");
    else if (ks == 6) asm volatile("s_waitcnt vmcnt(6)" ::: "memory");
    else              asm volatile("s_waitcnt vmcnt(0)" ::: "memory");

    const float* Ab = &As[ks % 3][0];
    float4 f0 = *reinterpret_cast<const float4*>(Ab + fo0);
    float4 f1 = *reinterpret_cast<const float4*>(Ab + fo1);
    uint4 ua;
    ua.x = __builtin_bit_cast(uint_t, __builtin_amdgcn_cvt_pkrtz(f0.x, f0.y));
    ua.y = __builtin_bit_cast(uint_t, __builtin_amdgcn_cvt_pkrtz(f0.z, f0.w));
    ua.z = __builtin_bit_cast(uint_t, __builtin_amdgcn_cvt_pkrtz(f1.x, f1.y));
    ua.w = __builtin_bit_cast(uint_t, __builtin_amdgcn_cvt_pkrtz(f1.z, f1.w));
    half8 a = __builtin_bit_cast(half8, ua);

    const char* bbase = (const char*)&Bs[ks % 3][0];
#pragma unroll
    for (int n = 0; n < 16; ++n) {
      half8 b = *reinterpret_cast<const half8*>(bbase + n * 1024 + lane * 16);
      acc[n] = __builtin_amdgcn_mfma_f32_16x16x32_f16(a, b, acc[n], 0, 0, 0);
    }
  }

  float attS[16], attD[16];
#pragma unroll
  for (int n = 0; n < 16; ++n) {
    attS[n] = att_src[n * 16 + l16];
    attD[n] = att_dst[n * 16 + l16];
  }

#pragma unroll
  for (int r = 0; r < 4; ++r) {
    int grow = row0 + wid * 16 + lhi * 4 + r;
    if (grow < M) {
#pragma unroll
      for (int n2 = 0; n2 < 4; ++n2) {
        uint_t pk01 = __builtin_bit_cast(uint_t,
            __builtin_amdgcn_cvt_pkrtz(acc[n2][r], acc[n2 + 4][r]));
        uint_t pk23 = __builtin_bit_cast(uint_t,
            __builtin_amdgcn_cvt_pkrtz(acc[n2 + 8][r], acc[n2 + 12][r]));
        Hmp[(size_t)grow * 64 + n2 * 16 + l16] = make_uint2(pk01, pk23);
      }
      float sv[4] = {0.f, 0.f, 0.f, 0.f}, dv[4] = {0.f, 0.f, 0.f, 0.f};
#pragma unroll
      for (int h = 0; h < 4; ++h)
#pragma unroll
        for (int j = 0; j < 4; ++j) {
          sv[h] += acc[h * 4 + j][r] * attS[h * 4 + j];
          dv[h] += acc[h * 4 + j][r] * attD[h * 4 + j];
        }
#pragma unroll
      for (int off = 1; off < 16; off <<= 1)
#pragma unroll
        for (int h = 0; h < 4; ++h) {
          sv[h] += __shfl_xor(sv[h], off, 16);
          dv[h] += __shfl_xor(dv[h], off, 16);
        }
      if (l16 == 0) {
#pragma unroll
        for (int h = 0; h < 4; ++h) {
          as_out[(size_t)grow * 4 + h] = sv[h];
          ad_out[(size_t)grow * 4 + h] = dv[h];
        }
      }
    }
  }
}

// ---------------- CSR build (scan1 adds +1 self-loop inline) ----------------
__global__ __launch_bounds__(256) void scan1(const int* __restrict__ deg,
                                             int* __restrict__ rp,
                                             int* __restrict__ bsum) {
  __shared__ int sh[256];
  int t = threadIdx.x;
  int base = blockIdx.x * 1024 + t * 4;
  int v[4];
#pragma unroll
  for (int i = 0; i < 4; ++i) v[i] = (base + i < N_NODES) ? (deg[base + i] + 1) : 0;
  int tsum = v[0] + v[1] + v[2] + v[3];
  sh[t] = tsum;
  __syncthreads();
  for (int off = 1; off < 256; off <<= 1) {
    int x = (t >= off) ? sh[t - off] : 0;
    __syncthreads();
    sh[t] += x;
    __syncthreads();
  }
  if (t == 255) bsum[blockIdx.x] = sh[255];
  int run = sh[t] - tsum;
#pragma unroll
  for (int i = 0; i < 4; ++i) {
    if (base + i < N_NODES) rp[base + i] = run;
    run += v[i];
  }
}

#define NBLK1 ((N_NODES + 1023) / 1024)  // 98

__global__ __launch_bounds__(128) void scan2(const int* __restrict__ bsum,
                                             int* __restrict__ boff) {
  __shared__ int sh[128];
  int t = threadIdx.x;
  int own = (t < NBLK1) ? bsum[t] : 0;
  sh[t] = own;
  __syncthreads();
  for (int off = 1; off < 128; off <<= 1) {
    int x = (t >= off) ? sh[t - off] : 0;
    __syncthreads();
    sh[t] += x;
    __syncthreads();
  }
  boff[t] = sh[t] - own;
}

__global__ __launch_bounds__(256) void scan3(int* __restrict__ rp,
                                             const int* __restrict__ boff,
                                             int* __restrict__ cursor) {
  int idx = blockIdx.x * 256 + threadIdx.x;
  if (idx < N_NODES) {
    int v = rp[idx] + boff[idx >> 10];
    rp[idx] = v;
    cursor[idx] = v;
  }
  if (idx == 0) rp[N_NODES] = TOT;
}

// scatter + fused edge-weight computation -> one 16B record {src, w01, w23, 0}
__global__ __launch_bounds__(256) void scatter_edges(const int* __restrict__ esrc,
                                                     const int* __restrict__ edst,
                                                     const float* __restrict__ as_buf,
                                                     const float* __restrict__ ad_buf,
                                                     int* __restrict__ cursor,
                                                     uint4* __restrict__ erec) {
  int e = blockIdx.x * 256 + threadIdx.x;
  if (e >= TOT) return;
  int s, d;
  if (e < N_EDGES) { s = esrc[e]; d = edst[e]; }
  else { s = e - N_EDGES; d = s; }
  int p = atomicAdd(&cursor[d], 1);
  float4 a1 = *reinterpret_cast<const float4*>(as_buf + (size_t)s * NHEAD);
  float4 a2 = *reinterpret_cast<const float4*>(ad_buf + (size_t)d * NHEAD);
  float e0 = a1.x + a2.x; e0 = e0 > 0.f ? e0 : NEG_SLOPE * e0;
  float e1 = a1.y + a2.y; e1 = e1 > 0.f ? e1 : NEG_SLOPE * e1;
  float e2 = a1.z + a2.z; e2 = e2 > 0.f ? e2 : NEG_SLOPE * e2;
  float e3 = a1.w + a2.w; e3 = e3 > 0.f ? e3 : NEG_SLOPE * e3;
  float w0 = __expf(e0 - 4.f), w1 = __expf(e1 - 4.f);
  float w2 = __expf(e2 - 4.f), w3 = __expf(e3 - 4.f);
  uint_t pk01 = __builtin_bit_cast(uint_t, __builtin_amdgcn_cvt_pkrtz(w0, w1));
  uint_t pk23 = __builtin_bit_cast(uint_t, __builtin_amdgcn_cvt_pkrtz(w2, w3));
  erec[p] = make_uint4((uint_t)s, pk01, pk23, 0u);
}

// ---------------- fused softmax + aggregation: main/tail split ----------------
static __device__ __forceinline__ void accum_edge(uint4 cur, uint4 hv, bool act,
                                                  float* acc, float* den) {
  uint_t w01u = act ? cur.y : 0u;
  uint_t w23u = act ? cur.z : 0u;
  h2v w01 = __builtin_bit_cast(h2v, w01u);
  h2v w23 = __builtin_bit_cast(h2v, w23u);
  h2v ha = __builtin_bit_cast(h2v, hv.x);
  h2v hb = __builtin_bit_cast(h2v, hv.y);
  h2v hc = __builtin_bit_cast(h2v, hv.z);
  h2v hd = __builtin_bit_cast(h2v, hv.w);
  acc[0] += (float)w01.x * (float)ha.x;
  acc[1] += (float)w01.y * (float)ha.y;
  acc[2] += (float)w23.x * (float)hb.x;
  acc[3] += (float)w23.y * (float)hb.y;
  acc[4] += (float)w01.x * (float)hc.x;
  acc[5] += (float)w01.y * (float)hc.y;
  acc[6] += (float)w23.x * (float)hd.x;
  acc[7] += (float)w23.y * (float)hd.y;
  den[0] += (float)w01.x;
  den[1] += (float)w01.y;
  den[2] += (float)w23.x;
  den[3] += (float)w23.y;
}

__global__ __launch_bounds__(256) void aggregate(const int* __restrict__ rp,
                                                 const uint4* __restrict__ erec,
                                                 const uint2* __restrict__ Hp,
                                                 const float* __restrict__ bias,
                                                 float* __restrict__ out) {
  int n = blockIdx.x * 4 + (threadIdx.x >> 6);
  int lane = threadIdx.x & 63;
  if (n >= N_NODES) return;
  const int half = lane >> 5;
  const uint_t off_lane = (uint_t)(lane & 31) << 4;
  const char* __restrict__ Hb = (const char*)Hp;

  int beg = rp[n], end = rp[n + 1];

  float acc[8] = {};
  float den[4] = {};

  int j = beg;
  // ---- main loop: 8 edges/iter, no clamps, no cndmasks ----
  // Prefetch overshoot (up to erec[end+14]) lands in the 16-record pad; those
  // values are only consumed if the loop continues, which implies in-bounds.
  if (j + 15 < end) {
    const uint4* ep = erec + j + half;
    uint4 r0 = ep[0], r1 = ep[2], r2 = ep[4], r3 = ep[6];
    for (; j + 15 < end; j += 8, ep += 8) {
      uint4 c0 = r0, c1 = r1, c2 = r2, c3 = r3;
      r0 = ep[8]; r1 = ep[10]; r2 = ep[12]; r3 = ep[14];
      uint4 h0 = *reinterpret_cast<const uint4*>(Hb + ((c0.x << 9) | off_lane));
      uint4 h1 = *reinterpret_cast<const uint4*>(Hb + ((c1.x << 9) | off_lane));
      uint4 h2 = *reinterpret_cast<const uint4*>(Hb + ((c2.x << 9) | off_lane));
      uint4 h3 = *reinterpret_cast<const uint4*>(Hb + ((c3.x << 9) | off_lane));
      accum_edge(c0, h0, true, acc, den);
      accum_edge(c1, h1, true, acc, den);
      accum_edge(c2, h2, true, acc, den);
      accum_edge(c3, h3, true, acc, den);
    }
  }
  // ---- tail: clamped (<= 2 iterations) ----
  if (j < end) {
    const int last = end - 1;
    int i0 = j + half;     if (i0 > last) i0 = last;
    int i1 = j + 2 + half; if (i1 > last) i1 = last;
    int i2 = j + 4 + half; if (i2 > last) i2 = last;
    int i3 = j + 6 + half; if (i3 > last) i3 = last;
    uint4 r0 = erec[i0], r1 = erec[i1], r2 = erec[i2], r3 = erec[i3];
    for (; j < end; j += 8) {
      uint4 c0 = r0, c1 = r1, c2 = r2, c3 = r3;
      i0 = j + 8 + half;  if (i0 > last) i0 = last;
      i1 = j + 10 + half; if (i1 > last) i1 = last;
      i2 = j + 12 + half; if (i2 > last) i2 = last;
      i3 = j + 14 + half; if (i3 > last) i3 = last;
      r0 = erec[i0]; r1 = erec[i1]; r2 = erec[i2]; r3 = erec[i3];
      uint4 h0 = *reinterpret_cast<const uint4*>(Hb + ((c0.x << 9) | off_lane));
      uint4 h1 = *reinterpret_cast<const uint4*>(Hb + ((c1.x << 9) | off_lane));
      uint4 h2 = *reinterpret_cast<const uint4*>(Hb + ((c2.x << 9) | off_lane));
      uint4 h3 = *reinterpret_cast<const uint4*>(Hb + ((c3.x << 9) | off_lane));
      accum_edge(c0, h0, (j + half) < end, acc, den);
      accum_edge(c1, h1, (j + 2 + half) < end, acc, den);
      accum_edge(c2, h2, (j + 4 + half) < end, acc, den);
      accum_edge(c3, h3, (j + 6 + half) < end, acc, den);
    }
  }

#pragma unroll
  for (int k = 0; k < 8; ++k) acc[k] += __shfl_xor(acc[k], 32, 64);
#pragma unroll
  for (int k = 0; k < 4; ++k) den[k] += __shfl_xor(den[k], 32, 64);

  if (lane < 32) {
    float i0v = 1.f / (den[0] + 1e-30f);
    float i1v = 1.f / (den[1] + 1e-30f);
    float i2v = 1.f / (den[2] + 1e-30f);
    float i3v = 1.f / (den[3] + 1e-30f);
    float2 b2 = *reinterpret_cast<const float2*>(bias + 2 * lane);
    float rA = 0.25f * (acc[0] * i0v + acc[1] * i1v + acc[2] * i2v + acc[3] * i3v) + b2.x;
    float rB = 0.25f * (acc[4] * i0v + acc[5] * i1v + acc[6] * i2v + acc[7] * i3v) + b2.y;
    *reinterpret_cast<float2*>(out + (size_t)n * CH + 2 * lane) = make_float2(rA, rB);
  }
}

extern "C" void kernel_launch(void* const* d_in, const int* in_sizes, int n_in,
                              void* d_out, int out_size, void* d_ws, size_t ws_size,
                              hipStream_t stream) {
  const float* x       = (const float*)d_in[0];
  const int*   eidx    = (const int*)d_in[1];
  const float* W       = (const float*)d_in[2];
  const float* att_src = (const float*)d_in[3];
  const float* att_dst = (const float*)d_in[4];
  const float* bias    = (const float*)d_in[5];
  float* out = (float*)d_out;

  uint2* Hmp    = (uint2*)d_ws;                               // N*64 uint2 (51.2MB)
  uint4* erec   = (uint4*)(Hmp + (size_t)N_NODES * 64);       // TOT+16 uint4 (27.2MB)
  float* as_buf = (float*)(erec + (size_t)TOT + 16);          // N*4
  float* ad_buf = as_buf + (size_t)N_NODES * NHEAD;           // N*4
  uint4* Wt_arr = (uint4*)(ad_buf + (size_t)N_NODES * NHEAD); // 8192 uint4 (128KB)
  int*   deg    = (int*)(Wt_arr + 8192);                      // N (reused as cursor)
  int*   rp     = deg + N_NODES;                              // N+1
  int*   bsum   = rp + N_NODES + 1;                           // 128
  int*   boff   = bsum + 128;                                 // 128

  const int* esrc = eidx;
  const int* edst = eidx + N_EDGES;

  conv_w<<<32, 256, 0, stream>>>(W, Wt_arr);
  hipMemsetAsync(deg, 0, (size_t)N_NODES * sizeof(int), stream);

  // grid-mix: 1563 GEMM blocks first, 391 deg-count blocks backfill the tail
  dim3 ggrid(NGEMM + DEG_BLOCKS);
  gemm_mfma<<<ggrid, 256, 0, stream>>>(x, Wt_arr, att_src, att_dst, Hmp, as_buf, ad_buf,
                                       edst, deg, N_NODES);

  scan1<<<NBLK1, 256, 0, stream>>>(deg, rp, bsum);
  scan2<<<1, 128, 0, stream>>>(bsum, boff);
  scan3<<<(N_NODES + 255) / 256, 256, 0, stream>>>(rp, boff, deg /*cursor*/);
  scatter_edges<<<(TOT + 255) / 256, 256, 0, stream>>>(esrc, edst, as_buf, ad_buf,
                                                       deg /*cursor*/, erec);

  aggregate<<<(N_NODES + 3) / 4, 256, 0, stream>>>(rp, erec, Hmp, bias, out);
}

// Round 17
// 316.242 us; speedup vs baseline: 1.0007x; 1.0007x over previous
//
#include <hip/hip_runtime.h>

#define N_NODES 100000
#define N_EDGES 1600000
#define TOT (N_EDGES + N_NODES)
#define IN_CH 256
#define NHEAD 4
#define CH 64
#define HC 256
#define NEG_SLOPE 0.2f
#define NGEMM ((N_NODES + 63) / 64)  // 1563 gemm blocks
#define DEG_BLOCKS 391               // 391*256*4 int4 >= 400,000

typedef _Float16 half8 __attribute__((ext_vector_type(8)));
typedef _Float16 h2v __attribute__((ext_vector_type(2)));
typedef float f32x4 __attribute__((ext_vector_type(4)));
typedef unsigned short ushort_t;
typedef unsigned int uint_t;

static __device__ __forceinline__ ushort_t f2h(float f) {
  _Float16 h = (_Float16)f;
  return __builtin_bit_cast(ushort_t, h);
}

// async global->LDS, 16B per lane (dest = wave-uniform base + lane*16)
static __device__ __forceinline__ void gload_lds16(const char* g, char* l) {
  __builtin_amdgcn_global_load_lds(
      (const __attribute__((address_space(1))) unsigned int*)g,
      (__attribute__((address_space(3))) unsigned int*)l, 16, 0, 0);
}

// ---------------- W fp32 [K=256][N=256] -> Wt_arr, MFMA-fragment-major ----------------
__global__ __launch_bounds__(256) void conv_w(const float* __restrict__ W,
                                              uint4* __restrict__ Wt_arr) {
  int id = blockIdx.x * 256 + threadIdx.x;  // 0..8191
  int lane = id & 63;
  int n = (id >> 6) & 15;
  int ks = id >> 10;
  int col = n * 16 + (lane & 15);
  int kbase = ks * 32 + (lane >> 4) * 8;
  ushort_t h[8];
#pragma unroll
  for (int j = 0; j < 8; ++j) h[j] = f2h(W[(size_t)(kbase + j) * HC + col]);
  uint4 u;
  u.x = (uint_t)h[0] | ((uint_t)h[1] << 16);
  u.y = (uint_t)h[2] | ((uint_t)h[3] << 16);
  u.z = (uint_t)h[4] | ((uint_t)h[5] << 16);
  u.w = (uint_t)h[6] | ((uint_t)h[7] << 16);
  Wt_arr[id] = u;
}

// ---------------- grid-mix: deg-count blocks FIRST (R15-measured best) ----------------
// GEMM: triple-buffered LDS staging, raw s_barrier + counted vmcnt (T3/T4).
__global__ __launch_bounds__(256) void gemm_mfma(const float* __restrict__ X,
                                                 const uint4* __restrict__ Wt_arr,
                                                 const float* __restrict__ att_src,
                                                 const float* __restrict__ att_dst,
                                                 uint2* __restrict__ Hmp,
                                                 float* __restrict__ as_out,
                                                 float* __restrict__ ad_out,
                                                 const int* __restrict__ edst,
                                                 int* __restrict__ deg, int M) {
  const int tid = threadIdx.x;

  if (blockIdx.x < DEG_BLOCKS) {  // degree-count blocks: no LDS, no barriers
#pragma unroll
    for (int i = 0; i < 4; ++i) {
      int t = (blockIdx.x * 4 + i) * 256 + tid;
      if (t < N_EDGES / 4) {
        int4 d4 = reinterpret_cast<const int4*>(edst)[t];
        atomicAdd(&deg[d4.x], 1);
        atomicAdd(&deg[d4.y], 1);
        atomicAdd(&deg[d4.z], 1);
        atomicAdd(&deg[d4.w], 1);
      }
    }
    return;
  }

  __shared__ uint4 Bs[3][1024];                // 3 x 16 KB
  __shared__ __align__(16) float As[3][2048];  // 3 x 8 KB (64 rows x 32 f32)
  const int lane = tid & 63;
  const int wid = tid >> 6;
  const int l16 = lane & 15;
  const int lhi = lane >> 4;
  const int row0 = (blockIdx.x - DEG_BLOCKS) * 64;

  const int arow = tid >> 3;
  const int aslot = tid & 7;
  int ga0 = row0 + arow;       if (ga0 >= M) ga0 = M - 1;
  int ga1 = row0 + arow + 32;  if (ga1 >= M) ga1 = M - 1;
  const int sslot = aslot ^ (arow & 7);
  const char* asrc0 = (const char*)X + (size_t)ga0 * 1024 + (sslot << 4);
  const char* asrc1 = (const char*)X + (size_t)ga1 * 1024 + (sslot << 4);

  const char* __restrict__ wsrc = (const char*)Wt_arr;

  const int frow = wid * 16 + l16;
  const int sw = frow & 7;
  const int fo0 = frow * 32 + (((2 * lhi + 0) ^ sw) << 2);
  const int fo1 = frow * 32 + (((2 * lhi + 1) ^ sw) << 2);

  auto ISSUE = [&](int kk, int b) {
    char* ad = (char*)&As[b][0] + tid * 16;
    gload_lds16(asrc0 + kk * 128, ad);
    gload_lds16(asrc1 + kk * 128, ad + 4096);
    char* bd = (char*)&Bs[b][0] + tid * 16;
    const char* s = wsrc + kk * 16384 + tid * 16;
    gload_lds16(s,         bd);
    gload_lds16(s + 4096,  bd + 4096);
    gload_lds16(s + 8192,  bd + 8192);
    gload_lds16(s + 12288, bd + 12288);
  };

  ISSUE(0, 0);
  ISSUE(1, 1);

  f32x4 acc[16] = {};

#pragma unroll
  for (int ks = 0; ks < 8; ++ks) {
    __builtin_amdgcn_s_barrier();
    if (ks < 6) ISSUE(ks + 2, (ks + 2) % 3);
    if (ks < 6)       asm volatile("s_waitcnt vmcnt(12)" ::: "memory");
    else if (ks == 6) asm volatile("s_waitcnt vmcnt(6)" ::: "memory");
    else              asm volatile("s_waitcnt vmcnt(0)" ::: "memory");

    const float* Ab = &As[ks % 3][0];
    float4 f0 = *reinterpret_cast<const float4*>(Ab + fo0);
    float4 f1 = *reinterpret_cast<const float4*>(Ab + fo1);
    uint4 ua;
    ua.x = __builtin_bit_cast(uint_t, __builtin_amdgcn_cvt_pkrtz(f0.x, f0.y));
    ua.y = __builtin_bit_cast(uint_t, __builtin_amdgcn_cvt_pkrtz(f0.z, f0.w));
    ua.z = __builtin_bit_cast(uint_t, __builtin_amdgcn_cvt_pkrtz(f1.x, f1.y));
    ua.w = __builtin_bit_cast(uint_t, __builtin_amdgcn_cvt_pkrtz(f1.z, f1.w));
    half8 a = __builtin_bit_cast(half8, ua);

    const char* bbase = (const char*)&Bs[ks % 3][0];
#pragma unroll
    for (int n = 0; n < 16; ++n) {
      half8 b = *reinterpret_cast<const half8*>(bbase + n * 1024 + lane * 16);
      acc[n] = __builtin_amdgcn_mfma_f32_16x16x32_f16(a, b, acc[n], 0, 0, 0);
    }
  }

  float attS[16], attD[16];
#pragma unroll
  for (int n = 0; n < 16; ++n) {
    attS[n] = att_src[n * 16 + l16];
    attD[n] = att_dst[n * 16 + l16];
  }

#pragma unroll
  for (int r = 0; r < 4; ++r) {
    int grow = row0 + wid * 16 + lhi * 4 + r;
    if (grow < M) {
#pragma unroll
      for (int n2 = 0; n2 < 4; ++n2) {
        uint_t pk01 = __builtin_bit_cast(uint_t,
            __builtin_amdgcn_cvt_pkrtz(acc[n2][r], acc[n2 + 4][r]));
        uint_t pk23 = __builtin_bit_cast(uint_t,
            __builtin_amdgcn_cvt_pkrtz(acc[n2 + 8][r], acc[n2 + 12][r]));
        Hmp[(size_t)grow * 64 + n2 * 16 + l16] = make_uint2(pk01, pk23);
      }
      float sv[4] = {0.f, 0.f, 0.f, 0.f}, dv[4] = {0.f, 0.f, 0.f, 0.f};
#pragma unroll
      for (int h = 0; h < 4; ++h)
#pragma unroll
        for (int j = 0; j < 4; ++j) {
          sv[h] += acc[h * 4 + j][r] * attS[h * 4 + j];
          dv[h] += acc[h * 4 + j][r] * attD[h * 4 + j];
        }
#pragma unroll
      for (int off = 1; off < 16; off <<= 1)
#pragma unroll
        for (int h = 0; h < 4; ++h) {
          sv[h] += __shfl_xor(sv[h], off, 16);
          dv[h] += __shfl_xor(dv[h], off, 16);
        }
      if (l16 == 0) {
#pragma unroll
        for (int h = 0; h < 4; ++h) {
          as_out[(size_t)grow * 4 + h] = sv[h];
          ad_out[(size_t)grow * 4 + h] = dv[h];
        }
      }
    }
  }
}

// ---------------- CSR build (scan1 adds +1 self-loop inline) ----------------
__global__ __launch_bounds__(256) void scan1(const int* __restrict__ deg,
                                             int* __restrict__ rp,
                                             int* __restrict__ bsum) {
  __shared__ int sh[256];
  int t = threadIdx.x;
  int base = blockIdx.x * 1024 + t * 4;
  int v[4];
#pragma unroll
  for (int i = 0; i < 4; ++i) v[i] = (base + i < N_NODES) ? (deg[base + i] + 1) : 0;
  int tsum = v[0] + v[1] + v[2] + v[3];
  sh[t] = tsum;
  __syncthreads();
  for (int off = 1; off < 256; off <<= 1) {
    int x = (t >= off) ? sh[t - off] : 0;
    __syncthreads();
    sh[t] += x;
    __syncthreads();
  }
  if (t == 255) bsum[blockIdx.x] = sh[255];
  int run = sh[t] - tsum;
#pragma unroll
  for (int i = 0; i < 4; ++i) {
    if (base + i < N_NODES) rp[base + i] = run;
    run += v[i];
  }
}

#define NBLK1 ((N_NODES + 1023) / 1024)  // 98

__global__ __launch_bounds__(128) void scan2(const int* __restrict__ bsum,
                                             int* __restrict__ boff) {
  __shared__ int sh[128];
  int t = threadIdx.x;
  int own = (t < NBLK1) ? bsum[t] : 0;
  sh[t] = own;
  __syncthreads();
  for (int off = 1; off < 128; off <<= 1) {
    int x = (t >= off) ? sh[t - off] : 0;
    __syncthreads();
    sh[t] += x;
    __syncthreads();
  }
  boff[t] = sh[t] - own;
}

__global__ __launch_bounds__(256) void scan3(int* __restrict__ rp,
                                             const int* __restrict__ boff,
                                             int* __restrict__ cursor) {
  int idx = blockIdx.x * 256 + threadIdx.x;
  if (idx < N_NODES) {
    int v = rp[idx] + boff[idx >> 10];
    rp[idx] = v;
    cursor[idx] = v;
  }
  if (idx == 0) rp[N_NODES] = TOT;
}

// scatter + fused edge-weight computation -> one 16B record {src, w01, w23, 0}
// 2 edges per thread (int2 edge loads, doubled per-thread MLP).
static __device__ __forceinline__ void scatter_one(int s, int d,
                                                   const float* __restrict__ as_buf,
                                                   const float* __restrict__ ad_buf,
                                                   int* __restrict__ cursor,
                                                   uint4* __restrict__ erec) {
  int p = atomicAdd(&cursor[d], 1);
  float4 a1 = *reinterpret_cast<const float4*>(as_buf + (size_t)s * NHEAD);
  float4 a2 = *reinterpret_cast<const float4*>(ad_buf + (size_t)d * NHEAD);
  float e0 = a1.x + a2.x; e0 = e0 > 0.f ? e0 : NEG_SLOPE * e0;
  float e1 = a1.y + a2.y; e1 = e1 > 0.f ? e1 : NEG_SLOPE * e1;
  float e2 = a1.z + a2.z; e2 = e2 > 0.f ? e2 : NEG_SLOPE * e2;
  float e3 = a1.w + a2.w; e3 = e3 > 0.f ? e3 : NEG_SLOPE * e3;
  float w0 = __expf(e0 - 4.f), w1 = __expf(e1 - 4.f);
  float w2 = __expf(e2 - 4.f), w3 = __expf(e3 - 4.f);
  uint_t pk01 = __builtin_bit_cast(uint_t, __builtin_amdgcn_cvt_pkrtz(w0, w1));
  uint_t pk23 = __builtin_bit_cast(uint_t, __builtin_amdgcn_cvt_pkrtz(w2, w3));
  erec[p] = make_uint4((uint_t)s, pk01, pk23, 0u);
}

__global__ __launch_bounds__(256) void scatter_edges(const int* __restrict__ esrc,
                                                     const int* __restrict__ edst,
                                                     const float* __restrict__ as_buf,
                                                     const float* __restrict__ ad_buf,
                                                     int* __restrict__ cursor,
                                                     uint4* __restrict__ erec) {
  int g = blockIdx.x * 256 + threadIdx.x;
  int e0 = 2 * g;
  if (e0 >= TOT) return;
  if (e0 + 1 < N_EDGES) {  // fast path: both real edges, vector loads
    int2 s2 = *reinterpret_cast<const int2*>(esrc + e0);
    int2 d2 = *reinterpret_cast<const int2*>(edst + e0);
    scatter_one(s2.x, d2.x, as_buf, ad_buf, cursor, erec);
    scatter_one(s2.y, d2.y, as_buf, ad_buf, cursor, erec);
  } else {
#pragma unroll
    for (int i = 0; i < 2; ++i) {
      int e = e0 + i;
      if (e >= TOT) break;
      int s, d;
      if (e < N_EDGES) { s = esrc[e]; d = edst[e]; }
      else { s = e - N_EDGES; d = s; }
      scatter_one(s, d, as_buf, ad_buf, cursor, erec);
    }
  }
}

// ---------------- fused softmax + aggregation: main/tail split (j+7 tuned) ----------
static __device__ __forceinline__ void accum_edge(uint4 cur, uint4 hv, bool act,
                                                  float* acc, float* den) {
  uint_t w01u = act ? cur.y : 0u;
  uint_t w23u = act ? cur.z : 0u;
  h2v w01 = __builtin_bit_cast(h2v, w01u);
  h2v w23 = __builtin_bit_cast(h2v, w23u);
  h2v ha = __builtin_bit_cast(h2v, hv.x);
  h2v hb = __builtin_bit_cast(h2v, hv.y);
  h2v hc = __builtin_bit_cast(h2v, hv.z);
  h2v hd = __builtin_bit_cast(h2v, hv.w);
  acc[0] += (float)w01.x * (float)ha.x;
  acc[1] += (float)w01.y * (float)ha.y;
  acc[2] += (float)w23.x * (float)hb.x;
  acc[3] += (float)w23.y * (float)hb.y;
  acc[4] += (float)w01.x * (float)hc.x;
  acc[5] += (float)w01.y * (float)hc.y;
  acc[6] += (float)w23.x * (float)hd.x;
  acc[7] += (float)w23.y * (float)hd.y;
  den[0] += (float)w01.x;
  den[1] += (float)w01.y;
  den[2] += (float)w23.x;
  den[3] += (float)w23.y;
}

__global__ __launch_bounds__(256) void aggregate(const int* __restrict__ rp,
                                                 const uint4* __restrict__ erec,
                                                 const uint2* __restrict__ Hp,
                                                 const float* __restrict__ bias,
                                                 float* __restrict__ out) {
  int n = blockIdx.x * 4 + (threadIdx.x >> 6);
  int lane = threadIdx.x & 63;
  if (n >= N_NODES) return;
  const int half = lane >> 5;
  const uint_t off_lane = (uint_t)(lane & 31) << 4;
  const char* __restrict__ Hb = (const char*)Hp;

  int beg = rp[n], end = rp[n + 1];

  float acc[8] = {};
  float den[4] = {};

  int j = beg;
  // ---- main loop: 8 fully-active edges per iter, no clamps ----
  // Runs while the current group of 8 (edges j..j+7) is entirely in-bounds.
  // Prefetch for the next group may overshoot into the 16-record zero pad; those
  // values are consumed only if the next iteration runs (which implies in-bounds).
  if (j + 7 < end) {
    const uint4* ep = erec + j + half;
    uint4 r0 = ep[0], r1 = ep[2], r2 = ep[4], r3 = ep[6];
    for (; j + 7 < end; j += 8, ep += 8) {
      uint4 c0 = r0, c1 = r1, c2 = r2, c3 = r3;
      r0 = ep[8]; r1 = ep[10]; r2 = ep[12]; r3 = ep[14];
      uint4 h0 = *reinterpret_cast<const uint4*>(Hb + ((c0.x << 9) | off_lane));
      uint4 h1 = *reinterpret_cast<const uint4*>(Hb + ((c1.x << 9) | off_lane));
      uint4 h2 = *reinterpret_cast<const uint4*>(Hb + ((c2.x << 9) | off_lane));
      uint4 h3 = *reinterpret_cast<const uint4*>(Hb + ((c3.x << 9) | off_lane));
      accum_edge(c0, h0, true, acc, den);
      accum_edge(c1, h1, true, acc, den);
      accum_edge(c2, h2, true, acc, den);
      accum_edge(c3, h3, true, acc, den);
    }
  }
  // ---- tail: clamped, at most 1 iteration (remaining < 8 edges) ----
  if (j < end) {
    const int last = end - 1;
    int i0 = j + half;     if (i0 > last) i0 = last;
    int i1 = j + 2 + half; if (i1 > last) i1 = last;
    int i2 = j + 4 + half; if (i2 > last) i2 = last;
    int i3 = j + 6 + half; if (i3 > last) i3 = last;
    uint4 c0 = erec[i0], c1 = erec[i1], c2 = erec[i2], c3 = erec[i3];
    uint4 h0 = *reinterpret_cast<const uint4*>(Hb + ((c0.x << 9) | off_lane));
    uint4 h1 = *reinterpret_cast<const uint4*>(Hb + ((c1.x << 9) | off_lane));
    uint4 h2 = *reinterpret_cast<const uint4*>(Hb + ((c2.x << 9) | off_lane));
    uint4 h3 = *reinterpret_cast<const uint4*>(Hb + ((c3.x << 9) | off_lane));
    accum_edge(c0, h0, (j + half) < end, acc, den);
    accum_edge(c1, h1, (j + 2 + half) < end, acc, den);
    accum_edge(c2, h2, (j + 4 + half) < end, acc, den);
    accum_edge(c3, h3, (j + 6 + half) < end, acc, den);
  }

#pragma unroll
  for (int k = 0; k < 8; ++k) acc[k] += __shfl_xor(acc[k], 32, 64);
#pragma unroll
  for (int k = 0; k < 4; ++k) den[k] += __shfl_xor(den[k], 32, 64);

  if (lane < 32) {
    float i0v = 1.f / (den[0] + 1e-30f);
    float i1v = 1.f / (den[1] + 1e-30f);
    float i2v = 1.f / (den[2] + 1e-30f);
    float i3v = 1.f / (den[3] + 1e-30f);
    float2 b2 = *reinterpret_cast<const float2*>(bias + 2 * lane);
    float rA = 0.25f * (acc[0] * i0v + acc[1] * i1v + acc[2] * i2v + acc[3] * i3v) + b2.x;
    float rB = 0.25f * (acc[4] * i0v + acc[5] * i1v + acc[6] * i2v + acc[7] * i3v) + b2.y;
    *reinterpret_cast<float2*>(out + (size_t)n * CH + 2 * lane) = make_float2(rA, rB);
  }
}

extern "C" void kernel_launch(void* const* d_in, const int* in_sizes, int n_in,
                              void* d_out, int out_size, void* d_ws, size_t ws_size,
                              hipStream_t stream) {
  const float* x       = (const float*)d_in[0];
  const int*   eidx    = (const int*)d_in[1];
  const float* W       = (const float*)d_in[2];
  const float* att_src = (const float*)d_in[3];
  const float* att_dst = (const float*)d_in[4];
  const float* bias    = (const float*)d_in[5];
  float* out = (float*)d_out;

  uint2* Hmp    = (uint2*)d_ws;                               // N*64 uint2 (51.2MB)
  uint4* erec   = (uint4*)(Hmp + (size_t)N_NODES * 64);       // TOT+16 uint4 (27.2MB)
  float* as_buf = (float*)(erec + (size_t)TOT + 16);          // N*4
  float* ad_buf = as_buf + (size_t)N_NODES * NHEAD;           // N*4
  uint4* Wt_arr = (uint4*)(ad_buf + (size_t)N_NODES * NHEAD); // 8192 uint4 (128KB)
  int*   deg    = (int*)(Wt_arr + 8192);                      // N (reused as cursor)
  int*   rp     = deg + N_NODES;                              // N+1
  int*   bsum   = rp + N_NODES + 1;                           // 128
  int*   boff   = bsum + 128;                                 // 128

  const int* esrc = eidx;
  const int* edst = eidx + N_EDGES;

  conv_w<<<32, 256, 0, stream>>>(W, Wt_arr);
  // zero deg + the 16 pad records past TOT (pad: 16 uint4 = 256B)
  hipMemsetAsync(deg, 0, (size_t)N_NODES * sizeof(int), stream);
  hipMemsetAsync(erec + (size_t)TOT, 0, 16 * sizeof(uint4), stream);

  // grid-mix: 391 deg-count blocks first, 1563 GEMM blocks (R15-measured best order)
  dim3 ggrid(DEG_BLOCKS + NGEMM);
  gemm_mfma<<<ggrid, 256, 0, stream>>>(x, Wt_arr, att_src, att_dst, Hmp, as_buf, ad_buf,
                                       edst, deg, N_NODES);

  scan1<<<NBLK1, 256, 0, stream>>>(deg, rp, bsum);
  scan2<<<1, 128, 0, stream>>>(bsum, boff);
  scan3<<<(N_NODES + 255) / 256, 256, 0, stream>>>(rp, boff, deg /*cursor*/);
  scatter_edges<<<((TOT + 1) / 2 + 255) / 256, 256, 0, stream>>>(esrc, edst, as_buf,
                                                                 ad_buf, deg /*cursor*/,
                                                                 erec);

  aggregate<<<(N_NODES + 3) / 4, 256, 0, stream>>>(rp, erec, Hmp, bias, out);
}

// Round 18
// 314.453 us; speedup vs baseline: 1.0064x; 1.0057x over previous
//
#include <hip/hip_runtime.h>

#define N_NODES 100000
#define N_EDGES 1600000
#define TOT (N_EDGES + N_NODES)
#define IN_CH 256
#define NHEAD 4
#define CH 64
#define HC 256
#define NEG_SLOPE 0.2f
#define NGEMM ((N_NODES + 63) / 64)  // 1563 gemm blocks
#define DEG_BLOCKS 391               // 391*256*4 int4 >= 400,000

typedef _Float16 half8 __attribute__((ext_vector_type(8)));
typedef float f32x4 __attribute__((ext_vector_type(4)));
typedef unsigned short ushort_t;
typedef unsigned int uint_t;

static __device__ __forceinline__ ushort_t f2h(float f) {
  _Float16 h = (_Float16)f;
  return __builtin_bit_cast(ushort_t, h);
}

// async global->LDS, 16B per lane (dest = wave-uniform base + lane*16)
static __device__ __forceinline__ void gload_lds16(const char* g, char* l) {
  __builtin_amdgcn_global_load_lds(
      (const __attribute__((address_space(1))) unsigned int*)g,
      (__attribute__((address_space(3))) unsigned int*)l, 16, 0, 0);
}

// ---------------- W fp32 [K=256][N=256] -> Wt_arr, MFMA-fragment-major ----------------
__global__ __launch_bounds__(256) void conv_w(const float* __restrict__ W,
                                              uint4* __restrict__ Wt_arr) {
  int id = blockIdx.x * 256 + threadIdx.x;  // 0..8191
  int lane = id & 63;
  int n = (id >> 6) & 15;
  int ks = id >> 10;
  int col = n * 16 + (lane & 15);
  int kbase = ks * 32 + (lane >> 4) * 8;
  ushort_t h[8];
#pragma unroll
  for (int j = 0; j < 8; ++j) h[j] = f2h(W[(size_t)(kbase + j) * HC + col]);
  uint4 u;
  u.x = (uint_t)h[0] | ((uint_t)h[1] << 16);
  u.y = (uint_t)h[2] | ((uint_t)h[3] << 16);
  u.z = (uint_t)h[4] | ((uint_t)h[5] << 16);
  u.w = (uint_t)h[6] | ((uint_t)h[7] << 16);
  Wt_arr[id] = u;
}

// ---------------- grid-mix: deg-count blocks FIRST (R15-measured best) ----------------
// GEMM: triple-buffered LDS staging, raw s_barrier + counted vmcnt (T3/T4).
__global__ __launch_bounds__(256) void gemm_mfma(const float* __restrict__ X,
                                                 const uint4* __restrict__ Wt_arr,
                                                 const float* __restrict__ att_src,
                                                 const float* __restrict__ att_dst,
                                                 uint2* __restrict__ Hmp,
                                                 float* __restrict__ as_out,
                                                 float* __restrict__ ad_out,
                                                 const int* __restrict__ edst,
                                                 int* __restrict__ deg, int M) {
  const int tid = threadIdx.x;

  if (blockIdx.x < DEG_BLOCKS) {  // degree-count blocks: no LDS, no barriers
#pragma unroll
    for (int i = 0; i < 4; ++i) {
      int t = (blockIdx.x * 4 + i) * 256 + tid;
      if (t < N_EDGES / 4) {
        int4 d4 = reinterpret_cast<const int4*>(edst)[t];
        atomicAdd(&deg[d4.x], 1);
        atomicAdd(&deg[d4.y], 1);
        atomicAdd(&deg[d4.z], 1);
        atomicAdd(&deg[d4.w], 1);
      }
    }
    return;
  }

  __shared__ uint4 Bs[3][1024];                // 3 x 16 KB
  __shared__ __align__(16) float As[3][2048];  // 3 x 8 KB (64 rows x 32 f32)
  const int lane = tid & 63;
  const int wid = tid >> 6;
  const int l16 = lane & 15;
  const int lhi = lane >> 4;
  const int row0 = (blockIdx.x - DEG_BLOCKS) * 64;

  const int arow = tid >> 3;
  const int aslot = tid & 7;
  int ga0 = row0 + arow;       if (ga0 >= M) ga0 = M - 1;
  int ga1 = row0 + arow + 32;  if (ga1 >= M) ga1 = M - 1;
  const int sslot = aslot ^ (arow & 7);
  const char* asrc0 = (const char*)X + (size_t)ga0 * 1024 + (sslot << 4);
  const char* asrc1 = (const char*)X + (size_t)ga1 * 1024 + (sslot << 4);

  const char* __restrict__ wsrc = (const char*)Wt_arr;

  const int frow = wid * 16 + l16;
  const int sw = frow & 7;
  const int fo0 = frow * 32 + (((2 * lhi + 0) ^ sw) << 2);
  const int fo1 = frow * 32 + (((2 * lhi + 1) ^ sw) << 2);

  auto ISSUE = [&](int kk, int b) {
    char* ad = (char*)&As[b][0] + tid * 16;
    gload_lds16(asrc0 + kk * 128, ad);
    gload_lds16(asrc1 + kk * 128, ad + 4096);
    char* bd = (char*)&Bs[b][0] + tid * 16;
    const char* s = wsrc + kk * 16384 + tid * 16;
    gload_lds16(s,         bd);
    gload_lds16(s + 4096,  bd + 4096);
    gload_lds16(s + 8192,  bd + 8192);
    gload_lds16(s + 12288, bd + 12288);
  };

  ISSUE(0, 0);
  ISSUE(1, 1);

  f32x4 acc[16] = {};

#pragma unroll
  for (int ks = 0; ks < 8; ++ks) {
    __builtin_amdgcn_s_barrier();
    if (ks < 6) ISSUE(ks + 2, (ks + 2) % 3);
    if (ks < 6)       asm volatile("s_waitcnt vmcnt(12)" ::: "memory");
    else if (ks == 6) asm volatile("s_waitcnt vmcnt(6)" ::: "memory");
    else              asm volatile("s_waitcnt vmcnt(0)" ::: "memory");

    const float* Ab = &As[ks % 3][0];
    float4 f0 = *reinterpret_cast<const float4*>(Ab + fo0);
    float4 f1 = *reinterpret_cast<const float4*>(Ab + fo1);
    uint4 ua;
    ua.x = __builtin_bit_cast(uint_t, __builtin_amdgcn_cvt_pkrtz(f0.x, f0.y));
    ua.y = __builtin_bit_cast(uint_t, __builtin_amdgcn_cvt_pkrtz(f0.z, f0.w));
    ua.z = __builtin_bit_cast(uint_t, __builtin_amdgcn_cvt_pkrtz(f1.x, f1.y));
    ua.w = __builtin_bit_cast(uint_t, __builtin_amdgcn_cvt_pkrtz(f1.z, f1.w));
    half8 a = __builtin_bit_cast(half8, ua);

    const char* bbase = (const char*)&Bs[ks % 3][0];
#pragma unroll
    for (int n = 0; n < 16; ++n) {
      half8 b = *reinterpret_cast<const half8*>(bbase + n * 1024 + lane * 16);
      acc[n] = __builtin_amdgcn_mfma_f32_16x16x32_f16(a, b, acc[n], 0, 0, 0);
    }
  }

  float attS[16], attD[16];
#pragma unroll
  for (int n = 0; n < 16; ++n) {
    attS[n] = att_src[n * 16 + l16];
    attD[n] = att_dst[n * 16 + l16];
  }

#pragma unroll
  for (int r = 0; r < 4; ++r) {
    int grow = row0 + wid * 16 + lhi * 4 + r;
    if (grow < M) {
#pragma unroll
      for (int n2 = 0; n2 < 4; ++n2) {
        uint_t pk01 = __builtin_bit_cast(uint_t,
            __builtin_amdgcn_cvt_pkrtz(acc[n2][r], acc[n2 + 4][r]));
        uint_t pk23 = __builtin_bit_cast(uint_t,
            __builtin_amdgcn_cvt_pkrtz(acc[n2 + 8][r], acc[n2 + 12][r]));
        Hmp[(size_t)grow * 64 + n2 * 16 + l16] = make_uint2(pk01, pk23);
      }
      float sv[4] = {0.f, 0.f, 0.f, 0.f}, dv[4] = {0.f, 0.f, 0.f, 0.f};
#pragma unroll
      for (int h = 0; h < 4; ++h)
#pragma unroll
        for (int j = 0; j < 4; ++j) {
          sv[h] += acc[h * 4 + j][r] * attS[h * 4 + j];
          dv[h] += acc[h * 4 + j][r] * attD[h * 4 + j];
        }
#pragma unroll
      for (int off = 1; off < 16; off <<= 1)
#pragma unroll
        for (int h = 0; h < 4; ++h) {
          sv[h] += __shfl_xor(sv[h], off, 16);
          dv[h] += __shfl_xor(dv[h], off, 16);
        }
      if (l16 == 0) {
#pragma unroll
        for (int h = 0; h < 4; ++h) {
          as_out[(size_t)grow * 4 + h] = sv[h];
          ad_out[(size_t)grow * 4 + h] = dv[h];
        }
      }
    }
  }
}

// ---------------- CSR build (scan1 adds +1 self-loop inline) ----------------
__global__ __launch_bounds__(256) void scan1(const int* __restrict__ deg,
                                             int* __restrict__ rp,
                                             int* __restrict__ bsum) {
  __shared__ int sh[256];
  int t = threadIdx.x;
  int base = blockIdx.x * 1024 + t * 4;
  int v[4];
#pragma unroll
  for (int i = 0; i < 4; ++i) v[i] = (base + i < N_NODES) ? (deg[base + i] + 1) : 0;
  int tsum = v[0] + v[1] + v[2] + v[3];
  sh[t] = tsum;
  __syncthreads();
  for (int off = 1; off < 256; off <<= 1) {
    int x = (t >= off) ? sh[t - off] : 0;
    __syncthreads();
    sh[t] += x;
    __syncthreads();
  }
  if (t == 255) bsum[blockIdx.x] = sh[255];
  int run = sh[t] - tsum;
#pragma unroll
  for (int i = 0; i < 4; ++i) {
    if (base + i < N_NODES) rp[base + i] = run;
    run += v[i];
  }
}

#define NBLK1 ((N_NODES + 1023) / 1024)  // 98

__global__ __launch_bounds__(128) void scan2(const int* __restrict__ bsum,
                                             int* __restrict__ boff) {
  __shared__ int sh[128];
  int t = threadIdx.x;
  int own = (t < NBLK1) ? bsum[t] : 0;
  sh[t] = own;
  __syncthreads();
  for (int off = 1; off < 128; off <<= 1) {
    int x = (t >= off) ? sh[t - off] : 0;
    __syncthreads();
    sh[t] += x;
    __syncthreads();
  }
  boff[t] = sh[t] - own;
}

__global__ __launch_bounds__(256) void scan3(int* __restrict__ rp,
                                             const int* __restrict__ boff,
                                             int* __restrict__ cursor) {
  int idx = blockIdx.x * 256 + threadIdx.x;
  if (idx < N_NODES) {
    int v = rp[idx] + boff[idx >> 10];
    rp[idx] = v;
    cursor[idx] = v;
  }
  if (idx == 0) rp[N_NODES] = TOT;
}

// scatter + fused edge-weight computation -> one 16B record {src, w01, w23, 0}
// (R15 form: 1 edge/thread - measured best)
__global__ __launch_bounds__(256) void scatter_edges(const int* __restrict__ esrc,
                                                     const int* __restrict__ edst,
                                                     const float* __restrict__ as_buf,
                                                     const float* __restrict__ ad_buf,
                                                     int* __restrict__ cursor,
                                                     uint4* __restrict__ erec) {
  int e = blockIdx.x * 256 + threadIdx.x;
  if (e >= TOT) return;
  int s, d;
  if (e < N_EDGES) { s = esrc[e]; d = edst[e]; }
  else { s = e - N_EDGES; d = s; }
  int p = atomicAdd(&cursor[d], 1);
  float4 a1 = *reinterpret_cast<const float4*>(as_buf + (size_t)s * NHEAD);
  float4 a2 = *reinterpret_cast<const float4*>(ad_buf + (size_t)d * NHEAD);
  float e0 = a1.x + a2.x; e0 = e0 > 0.f ? e0 : NEG_SLOPE * e0;
  float e1 = a1.y + a2.y; e1 = e1 > 0.f ? e1 : NEG_SLOPE * e1;
  float e2 = a1.z + a2.z; e2 = e2 > 0.f ? e2 : NEG_SLOPE * e2;
  float e3 = a1.w + a2.w; e3 = e3 > 0.f ? e3 : NEG_SLOPE * e3;
  float w0 = __expf(e0 - 4.f), w1 = __expf(e1 - 4.f);
  float w2 = __expf(e2 - 4.f), w3 = __expf(e3 - 4.f);
  uint_t pk01 = __builtin_bit_cast(uint_t, __builtin_amdgcn_cvt_pkrtz(w0, w1));
  uint_t pk23 = __builtin_bit_cast(uint_t, __builtin_amdgcn_cvt_pkrtz(w2, w3));
  erec[p] = make_uint4((uint_t)s, pk01, pk23, 0u);
}

// ---------------- fused softmax + aggregation: v_fma_mix inner loop ----------------
// Per edge per lane: 8 acc + 4 den single-instruction fp16xfp16+fp32 FMAs (no cvts).
static __device__ __forceinline__ void accum_mix(uint_t w01u, uint_t w23u, uint4 hv,
                                                 float* acc, float* den, float one) {
  asm("v_fma_mix_f32 %0, %1, %2, %0 op_sel:[0,0,0] op_sel_hi:[1,1,0]"
      : "+v"(acc[0]) : "v"(w01u), "v"(hv.x));
  asm("v_fma_mix_f32 %0, %1, %2, %0 op_sel:[1,1,0] op_sel_hi:[1,1,0]"
      : "+v"(acc[1]) : "v"(w01u), "v"(hv.x));
  asm("v_fma_mix_f32 %0, %1, %2, %0 op_sel:[0,0,0] op_sel_hi:[1,1,0]"
      : "+v"(acc[2]) : "v"(w23u), "v"(hv.y));
  asm("v_fma_mix_f32 %0, %1, %2, %0 op_sel:[1,1,0] op_sel_hi:[1,1,0]"
      : "+v"(acc[3]) : "v"(w23u), "v"(hv.y));
  asm("v_fma_mix_f32 %0, %1, %2, %0 op_sel:[0,0,0] op_sel_hi:[1,1,0]"
      : "+v"(acc[4]) : "v"(w01u), "v"(hv.z));
  asm("v_fma_mix_f32 %0, %1, %2, %0 op_sel:[1,1,0] op_sel_hi:[1,1,0]"
      : "+v"(acc[5]) : "v"(w01u), "v"(hv.z));
  asm("v_fma_mix_f32 %0, %1, %2, %0 op_sel:[0,0,0] op_sel_hi:[1,1,0]"
      : "+v"(acc[6]) : "v"(w23u), "v"(hv.w));
  asm("v_fma_mix_f32 %0, %1, %2, %0 op_sel:[1,1,0] op_sel_hi:[1,1,0]"
      : "+v"(acc[7]) : "v"(w23u), "v"(hv.w));
  asm("v_fma_mix_f32 %0, %1, %2, %0 op_sel:[0,0,0] op_sel_hi:[1,0,0]"
      : "+v"(den[0]) : "v"(w01u), "v"(one));
  asm("v_fma_mix_f32 %0, %1, %2, %0 op_sel:[1,0,0] op_sel_hi:[1,0,0]"
      : "+v"(den[1]) : "v"(w01u), "v"(one));
  asm("v_fma_mix_f32 %0, %1, %2, %0 op_sel:[0,0,0] op_sel_hi:[1,0,0]"
      : "+v"(den[2]) : "v"(w23u), "v"(one));
  asm("v_fma_mix_f32 %0, %1, %2, %0 op_sel:[1,0,0] op_sel_hi:[1,0,0]"
      : "+v"(den[3]) : "v"(w23u), "v"(one));
}

__global__ __launch_bounds__(256) void aggregate(const int* __restrict__ rp,
                                                 const uint4* __restrict__ erec,
                                                 const uint2* __restrict__ Hp,
                                                 const float* __restrict__ bias,
                                                 float* __restrict__ out) {
  int n = blockIdx.x * 4 + (threadIdx.x >> 6);
  int lane = threadIdx.x & 63;
  if (n >= N_NODES) return;
  const int half = lane >> 5;
  const uint_t off_lane = (uint_t)(lane & 31) << 4;
  const char* __restrict__ Hb = (const char*)Hp;
  const float one = 1.0f;

  int beg = rp[n], end = rp[n + 1];

  float acc[8] = {};
  float den[4] = {};

  int j = beg;
  // ---- main loop: 8 fully-active edges per iter, no clamps ----
  if (j + 7 < end) {
    const uint4* ep = erec + j + half;
    uint4 r0 = ep[0], r1 = ep[2], r2 = ep[4], r3 = ep[6];
    for (; j + 7 < end; j += 8, ep += 8) {
      uint4 c0 = r0, c1 = r1, c2 = r2, c3 = r3;
      r0 = ep[8]; r1 = ep[10]; r2 = ep[12]; r3 = ep[14];
      uint4 h0 = *reinterpret_cast<const uint4*>(Hb + ((c0.x << 9) | off_lane));
      uint4 h1 = *reinterpret_cast<const uint4*>(Hb + ((c1.x << 9) | off_lane));
      uint4 h2 = *reinterpret_cast<const uint4*>(Hb + ((c2.x << 9) | off_lane));
      uint4 h3 = *reinterpret_cast<const uint4*>(Hb + ((c3.x << 9) | off_lane));
      accum_mix(c0.y, c0.z, h0, acc, den, one);
      accum_mix(c1.y, c1.z, h1, acc, den, one);
      accum_mix(c2.y, c2.z, h2, acc, den, one);
      accum_mix(c3.y, c3.z, h3, acc, den, one);
    }
  }
  // ---- tail: clamped, at most 1 iteration (remaining < 8 edges) ----
  if (j < end) {
    const int last = end - 1;
    int i0 = j + half;     if (i0 > last) i0 = last;
    int i1 = j + 2 + half; if (i1 > last) i1 = last;
    int i2 = j + 4 + half; if (i2 > last) i2 = last;
    int i3 = j + 6 + half; if (i3 > last) i3 = last;
    uint4 c0 = erec[i0], c1 = erec[i1], c2 = erec[i2], c3 = erec[i3];
    uint4 h0 = *reinterpret_cast<const uint4*>(Hb + ((c0.x << 9) | off_lane));
    uint4 h1 = *reinterpret_cast<const uint4*>(Hb + ((c1.x << 9) | off_lane));
    uint4 h2 = *reinterpret_cast<const uint4*>(Hb + ((c2.x << 9) | off_lane));
    uint4 h3 = *reinterpret_cast<const uint4*>(Hb + ((c3.x << 9) | off_lane));
    uint_t w01, w23;
    w01 = (j + half) < end ? c0.y : 0u;     w23 = (j + half) < end ? c0.z : 0u;
    accum_mix(w01, w23, h0, acc, den, one);
    w01 = (j + 2 + half) < end ? c1.y : 0u; w23 = (j + 2 + half) < end ? c1.z : 0u;
    accum_mix(w01, w23, h1, acc, den, one);
    w01 = (j + 4 + half) < end ? c2.y : 0u; w23 = (j + 4 + half) < end ? c2.z : 0u;
    accum_mix(w01, w23, h2, acc, den, one);
    w01 = (j + 6 + half) < end ? c3.y : 0u; w23 = (j + 6 + half) < end ? c3.z : 0u;
    accum_mix(w01, w23, h3, acc, den, one);
  }

#pragma unroll
  for (int k = 0; k < 8; ++k) acc[k] += __shfl_xor(acc[k], 32, 64);
#pragma unroll
  for (int k = 0; k < 4; ++k) den[k] += __shfl_xor(den[k], 32, 64);

  if (lane < 32) {
    float i0v = 1.f / (den[0] + 1e-30f);
    float i1v = 1.f / (den[1] + 1e-30f);
    float i2v = 1.f / (den[2] + 1e-30f);
    float i3v = 1.f / (den[3] + 1e-30f);
    float2 b2 = *reinterpret_cast<const float2*>(bias + 2 * lane);
    float rA = 0.25f * (acc[0] * i0v + acc[1] * i1v + acc[2] * i2v + acc[3] * i3v) + b2.x;
    float rB = 0.25f * (acc[4] * i0v + acc[5] * i1v + acc[6] * i2v + acc[7] * i3v) + b2.y;
    *reinterpret_cast<float2*>(out + (size_t)n * CH + 2 * lane) = make_float2(rA, rB);
  }
}

extern "C" void kernel_launch(void* const* d_in, const int* in_sizes, int n_in,
                              void* d_out, int out_size, void* d_ws, size_t ws_size,
                              hipStream_t stream) {
  const float* x       = (const float*)d_in[0];
  const int*   eidx    = (const int*)d_in[1];
  const float* W       = (const float*)d_in[2];
  const float* att_src = (const float*)d_in[3];
  const float* att_dst = (const float*)d_in[4];
  const float* bias    = (const float*)d_in[5];
  float* out = (float*)d_out;

  uint2* Hmp    = (uint2*)d_ws;                               // N*64 uint2 (51.2MB)
  uint4* erec   = (uint4*)(Hmp + (size_t)N_NODES * 64);       // TOT+16 uint4 (27.2MB)
  float* as_buf = (float*)(erec + (size_t)TOT + 16);          // N*4
  float* ad_buf = as_buf + (size_t)N_NODES * NHEAD;           // N*4
  uint4* Wt_arr = (uint4*)(ad_buf + (size_t)N_NODES * NHEAD); // 8192 uint4 (128KB)
  int*   deg    = (int*)(Wt_arr + 8192);                      // N (reused as cursor)
  int*   rp     = deg + N_NODES;                              // N+1
  int*   bsum   = rp + N_NODES + 1;                           // 128
  int*   boff   = bsum + 128;                                 // 128

  const int* esrc = eidx;
  const int* edst = eidx + N_EDGES;

  conv_w<<<32, 256, 0, stream>>>(W, Wt_arr);
  hipMemsetAsync(deg, 0, (size_t)N_NODES * sizeof(int), stream);
  hipMemsetAsync(erec + (size_t)TOT, 0, 16 * sizeof(uint4), stream);

  // grid-mix: 391 deg-count blocks first, 1563 GEMM blocks (R15-measured best order)
  dim3 ggrid(DEG_BLOCKS + NGEMM);
  gemm_mfma<<<ggrid, 256, 0, stream>>>(x, Wt_arr, att_src, att_dst, Hmp, as_buf, ad_buf,
                                       edst, deg, N_NODES);

  scan1<<<NBLK1, 256, 0, stream>>>(deg, rp, bsum);
  scan2<<<1, 128, 0, stream>>>(bsum, boff);
  scan3<<<(N_NODES + 255) / 256, 256, 0, stream>>>(rp, boff, deg /*cursor*/);
  scatter_edges<<<(TOT + 255) / 256, 256, 0, stream>>>(esrc, edst, as_buf, ad_buf,
                                                       deg /*cursor*/, erec);

  aggregate<<<(N_NODES + 3) / 4, 256, 0, stream>>>(rp, erec, Hmp, bias, out);
}

// Round 19
// 309.583 us; speedup vs baseline: 1.0222x; 1.0157x over previous
//
#include <hip/hip_runtime.h>

#define N_NODES 100000
#define N_EDGES 1600000
#define TOT (N_EDGES + N_NODES)
#define IN_CH 256
#define NHEAD 4
#define CH 64
#define HC 256
#define NEG_SLOPE 0.2f
#define NGEMM ((N_NODES + 63) / 64)  // 1563 gemm blocks
#define DEG_BLOCKS 391               // 391*256*4 int4 >= 400,000
#define NBLK1 ((N_NODES + 1023) / 1024)  // 98

typedef _Float16 half8 __attribute__((ext_vector_type(8)));
typedef _Float16 h2v __attribute__((ext_vector_type(2)));
typedef float f32x4 __attribute__((ext_vector_type(4)));
typedef unsigned short ushort_t;
typedef unsigned int uint_t;

static __device__ __forceinline__ ushort_t f2h(float f) {
  _Float16 h = (_Float16)f;
  return __builtin_bit_cast(ushort_t, h);
}

// async global->LDS, 16B per lane (dest = wave-uniform base + lane*16)
static __device__ __forceinline__ void gload_lds16(const char* g, char* l) {
  __builtin_amdgcn_global_load_lds(
      (const __attribute__((address_space(1))) unsigned int*)g,
      (__attribute__((address_space(3))) unsigned int*)l, 16, 0, 0);
}

// ---------------- W fp32 -> Wt_arr (MFMA-fragment-major) + deg zeroing ----------------
__global__ __launch_bounds__(256) void conv_w(const float* __restrict__ W,
                                              uint4* __restrict__ Wt_arr,
                                              int* __restrict__ deg) {
  int id = blockIdx.x * 256 + threadIdx.x;  // 0..8191
  int lane = id & 63;
  int n = (id >> 6) & 15;
  int ks = id >> 10;
  int col = n * 16 + (lane & 15);
  int kbase = ks * 32 + (lane >> 4) * 8;
  ushort_t h[8];
#pragma unroll
  for (int j = 0; j < 8; ++j) h[j] = f2h(W[(size_t)(kbase + j) * HC + col]);
  uint4 u;
  u.x = (uint_t)h[0] | ((uint_t)h[1] << 16);
  u.y = (uint_t)h[2] | ((uint_t)h[3] << 16);
  u.z = (uint_t)h[4] | ((uint_t)h[5] << 16);
  u.w = (uint_t)h[6] | ((uint_t)h[7] << 16);
  Wt_arr[id] = u;
  // fused deg zeroing (replaces a memset launch): 25000 int4 = 100000 ints
  for (int i = id; i < N_NODES / 4; i += 8192)
    reinterpret_cast<int4*>(deg)[i] = make_int4(0, 0, 0, 0);
}

// ---------------- grid-mix: deg-count blocks FIRST (R15-measured best) ----------------
// GEMM: triple-buffered LDS staging, raw s_barrier + counted vmcnt (T3/T4).
__global__ __launch_bounds__(256) void gemm_mfma(const float* __restrict__ X,
                                                 const uint4* __restrict__ Wt_arr,
                                                 const float* __restrict__ att_src,
                                                 const float* __restrict__ att_dst,
                                                 uint2* __restrict__ Hmp,
                                                 float* __restrict__ as_out,
                                                 float* __restrict__ ad_out,
                                                 const int* __restrict__ edst,
                                                 int* __restrict__ deg, int M) {
  const int tid = threadIdx.x;

  if (blockIdx.x < DEG_BLOCKS) {  // degree-count blocks: no LDS use, no barriers
#pragma unroll
    for (int i = 0; i < 4; ++i) {
      int t = (blockIdx.x * 4 + i) * 256 + tid;
      if (t < N_EDGES / 4) {
        int4 d4 = reinterpret_cast<const int4*>(edst)[t];
        atomicAdd(&deg[d4.x], 1);
        atomicAdd(&deg[d4.y], 1);
        atomicAdd(&deg[d4.z], 1);
        atomicAdd(&deg[d4.w], 1);
      }
    }
    return;
  }

  __shared__ uint4 Bs[3][1024];                // 3 x 16 KB
  __shared__ __align__(16) float As[3][2048];  // 3 x 8 KB (64 rows x 32 f32)
  const int lane = tid & 63;
  const int wid = tid >> 6;
  const int l16 = lane & 15;
  const int lhi = lane >> 4;
  const int row0 = (blockIdx.x - DEG_BLOCKS) * 64;

  const int arow = tid >> 3;
  const int aslot = tid & 7;
  int ga0 = row0 + arow;       if (ga0 >= M) ga0 = M - 1;
  int ga1 = row0 + arow + 32;  if (ga1 >= M) ga1 = M - 1;
  const int sslot = aslot ^ (arow & 7);
  const char* asrc0 = (const char*)X + (size_t)ga0 * 1024 + (sslot << 4);
  const char* asrc1 = (const char*)X + (size_t)ga1 * 1024 + (sslot << 4);

  const char* __restrict__ wsrc = (const char*)Wt_arr;

  const int frow = wid * 16 + l16;
  const int sw = frow & 7;
  const int fo0 = frow * 32 + (((2 * lhi + 0) ^ sw) << 2);
  const int fo1 = frow * 32 + (((2 * lhi + 1) ^ sw) << 2);

  auto ISSUE = [&](int kk, int b) {
    char* ad = (char*)&As[b][0] + tid * 16;
    gload_lds16(asrc0 + kk * 128, ad);
    gload_lds16(asrc1 + kk * 128, ad + 4096);
    char* bd = (char*)&Bs[b][0] + tid * 16;
    const char* s = wsrc + kk * 16384 + tid * 16;
    gload_lds16(s,         bd);
    gload_lds16(s + 4096,  bd + 4096);
    gload_lds16(s + 8192,  bd + 8192);
    gload_lds16(s + 12288, bd + 12288);
  };

  ISSUE(0, 0);
  ISSUE(1, 1);

  f32x4 acc[16] = {};

#pragma unroll
  for (int ks = 0; ks < 8; ++ks) {
    __builtin_amdgcn_s_barrier();
    if (ks < 6) ISSUE(ks + 2, (ks + 2) % 3);
    if (ks < 6)       asm volatile("s_waitcnt vmcnt(12)" ::: "memory");
    else if (ks == 6) asm volatile("s_waitcnt vmcnt(6)" ::: "memory");
    else              asm volatile("s_waitcnt vmcnt(0)" ::: "memory");

    const float* Ab = &As[ks % 3][0];
    float4 f0 = *reinterpret_cast<const float4*>(Ab + fo0);
    float4 f1 = *reinterpret_cast<const float4*>(Ab + fo1);
    uint4 ua;
    ua.x = __builtin_bit_cast(uint_t, __builtin_amdgcn_cvt_pkrtz(f0.x, f0.y));
    ua.y = __builtin_bit_cast(uint_t, __builtin_amdgcn_cvt_pkrtz(f0.z, f0.w));
    ua.z = __builtin_bit_cast(uint_t, __builtin_amdgcn_cvt_pkrtz(f1.x, f1.y));
    ua.w = __builtin_bit_cast(uint_t, __builtin_amdgcn_cvt_pkrtz(f1.z, f1.w));
    half8 a = __builtin_bit_cast(half8, ua);

    const char* bbase = (const char*)&Bs[ks % 3][0];
#pragma unroll
    for (int n = 0; n < 16; ++n) {
      half8 b = *reinterpret_cast<const half8*>(bbase + n * 1024 + lane * 16);
      acc[n] = __builtin_amdgcn_mfma_f32_16x16x32_f16(a, b, acc[n], 0, 0, 0);
    }
  }

  float attS[16], attD[16];
#pragma unroll
  for (int n = 0; n < 16; ++n) {
    attS[n] = att_src[n * 16 + l16];
    attD[n] = att_dst[n * 16 + l16];
  }

#pragma unroll
  for (int r = 0; r < 4; ++r) {
    int grow = row0 + wid * 16 + lhi * 4 + r;
    if (grow < M) {
#pragma unroll
      for (int n2 = 0; n2 < 4; ++n2) {
        uint_t pk01 = __builtin_bit_cast(uint_t,
            __builtin_amdgcn_cvt_pkrtz(acc[n2][r], acc[n2 + 4][r]));
        uint_t pk23 = __builtin_bit_cast(uint_t,
            __builtin_amdgcn_cvt_pkrtz(acc[n2 + 8][r], acc[n2 + 12][r]));
        Hmp[(size_t)grow * 64 + n2 * 16 + l16] = make_uint2(pk01, pk23);
      }
      float sv[4] = {0.f, 0.f, 0.f, 0.f}, dv[4] = {0.f, 0.f, 0.f, 0.f};
#pragma unroll
      for (int h = 0; h < 4; ++h)
#pragma unroll
        for (int j = 0; j < 4; ++j) {
          sv[h] += acc[h * 4 + j][r] * attS[h * 4 + j];
          dv[h] += acc[h * 4 + j][r] * attD[h * 4 + j];
        }
#pragma unroll
      for (int off = 1; off < 16; off <<= 1)
#pragma unroll
        for (int h = 0; h < 4; ++h) {
          sv[h] += __shfl_xor(sv[h], off, 16);
          dv[h] += __shfl_xor(dv[h], off, 16);
        }
      if (l16 == 0) {
#pragma unroll
        for (int h = 0; h < 4; ++h) {
          as_out[(size_t)grow * 4 + h] = sv[h];
          ad_out[(size_t)grow * 4 + h] = dv[h];
        }
      }
    }
  }
}

// ---------------- CSR build (scan1 adds +1 self-loop inline) ----------------
__global__ __launch_bounds__(256) void scan1(const int* __restrict__ deg,
                                             int* __restrict__ rp,
                                             int* __restrict__ bsum) {
  __shared__ int sh[256];
  int t = threadIdx.x;
  int base = blockIdx.x * 1024 + t * 4;
  int v[4];
#pragma unroll
  for (int i = 0; i < 4; ++i) v[i] = (base + i < N_NODES) ? (deg[base + i] + 1) : 0;
  int tsum = v[0] + v[1] + v[2] + v[3];
  sh[t] = tsum;
  __syncthreads();
  for (int off = 1; off < 256; off <<= 1) {
    int x = (t >= off) ? sh[t - off] : 0;
    __syncthreads();
    sh[t] += x;
    __syncthreads();
  }
  if (t == 255) bsum[blockIdx.x] = sh[255];
  int run = sh[t] - tsum;
#pragma unroll
  for (int i = 0; i < 4; ++i) {
    if (base + i < N_NODES) rp[base + i] = run;
    run += v[i];
  }
}

// merged scan2+scan3: each block locally scans bsum (98 entries) in LDS, then
// applies its chunk's exclusive offset. Saves one launch + dependency bubble.
__global__ __launch_bounds__(256) void scan23(int* __restrict__ rp,
                                              const int* __restrict__ bsum,
                                              int* __restrict__ cursor) {
  __shared__ int inc[128];
  int t = threadIdx.x;
  if (t < 128) inc[t] = (t < NBLK1) ? bsum[t] : 0;
  __syncthreads();
  for (int off = 1; off < 128; off <<= 1) {
    int x = 0;
    if (t < 128 && t >= off) x = inc[t - off];
    __syncthreads();
    if (t < 128) inc[t] += x;
    __syncthreads();
  }
  int idx = blockIdx.x * 256 + t;
  if (idx < N_NODES) {
    int c = idx >> 10;
    int boff = inc[c] - bsum[c];  // exclusive = inclusive - own
    int v = rp[idx] + boff;
    rp[idx] = v;
    cursor[idx] = v;
  }
  if (idx == 0) rp[N_NODES] = TOT;
}

// scatter + fused edge-weight computation -> one 16B record {src, w01, w23, 0}
__global__ __launch_bounds__(256) void scatter_edges(const int* __restrict__ esrc,
                                                     const int* __restrict__ edst,
                                                     const float* __restrict__ as_buf,
                                                     const float* __restrict__ ad_buf,
                                                     int* __restrict__ cursor,
                                                     uint4* __restrict__ erec) {
  int e = blockIdx.x * 256 + threadIdx.x;
  if (e >= TOT) return;
  int s, d;
  if (e < N_EDGES) { s = esrc[e]; d = edst[e]; }
  else { s = e - N_EDGES; d = s; }
  int p = atomicAdd(&cursor[d], 1);
  float4 a1 = *reinterpret_cast<const float4*>(as_buf + (size_t)s * NHEAD);
  float4 a2 = *reinterpret_cast<const float4*>(ad_buf + (size_t)d * NHEAD);
  float e0 = a1.x + a2.x; e0 = e0 > 0.f ? e0 : NEG_SLOPE * e0;
  float e1 = a1.y + a2.y; e1 = e1 > 0.f ? e1 : NEG_SLOPE * e1;
  float e2 = a1.z + a2.z; e2 = e2 > 0.f ? e2 : NEG_SLOPE * e2;
  float e3 = a1.w + a2.w; e3 = e3 > 0.f ? e3 : NEG_SLOPE * e3;
  // exp(e-4): shift cancels in softmax ratio, keeps fp16 in safe range
  float w0 = __expf(e0 - 4.f), w1 = __expf(e1 - 4.f);
  float w2 = __expf(e2 - 4.f), w3 = __expf(e3 - 4.f);
  uint_t pk01 = __builtin_bit_cast(uint_t, __builtin_amdgcn_cvt_pkrtz(w0, w1));
  uint_t pk23 = __builtin_bit_cast(uint_t, __builtin_amdgcn_cvt_pkrtz(w2, w3));
  erec[p] = make_uint4((uint_t)s, pk01, pk23, 0u);
}

// ---------------- fused softmax + aggregation: 8 edges/iter (R15 clamped form) -------
static __device__ __forceinline__ void accum_edge(uint4 cur, uint4 hv, bool act,
                                                  float* acc, float* den) {
  uint_t w01u = act ? cur.y : 0u;
  uint_t w23u = act ? cur.z : 0u;
  h2v w01 = __builtin_bit_cast(h2v, w01u);
  h2v w23 = __builtin_bit_cast(h2v, w23u);
  h2v ha = __builtin_bit_cast(h2v, hv.x);
  h2v hb = __builtin_bit_cast(h2v, hv.y);
  h2v hc = __builtin_bit_cast(h2v, hv.z);
  h2v hd = __builtin_bit_cast(h2v, hv.w);
  acc[0] += (float)w01.x * (float)ha.x;
  acc[1] += (float)w01.y * (float)ha.y;
  acc[2] += (float)w23.x * (float)hb.x;
  acc[3] += (float)w23.y * (float)hb.y;
  acc[4] += (float)w01.x * (float)hc.x;
  acc[5] += (float)w01.y * (float)hc.y;
  acc[6] += (float)w23.x * (float)hd.x;
  acc[7] += (float)w23.y * (float)hd.y;
  den[0] += (float)w01.x;
  den[1] += (float)w01.y;
  den[2] += (float)w23.x;
  den[3] += (float)w23.y;
}

__global__ __launch_bounds__(256) void aggregate(const int* __restrict__ rp,
                                                 const uint4* __restrict__ erec,
                                                 const uint2* __restrict__ Hp,
                                                 const float* __restrict__ bias,
                                                 float* __restrict__ out) {
  int n = blockIdx.x * 4 + (threadIdx.x >> 6);
  int lane = threadIdx.x & 63;
  if (n >= N_NODES) return;
  const int half = lane >> 5;
  const uint_t off_lane = (uint_t)(lane & 31) << 4;
  const char* __restrict__ Hb = (const char*)Hp;

  int beg = rp[n], end = rp[n + 1];
  const int last = end - 1;

  float acc[8] = {};
  float den[4] = {};

  int i0 = beg + half;     if (i0 > last) i0 = last;
  int i1 = beg + 2 + half; if (i1 > last) i1 = last;
  int i2 = beg + 4 + half; if (i2 > last) i2 = last;
  int i3 = beg + 6 + half; if (i3 > last) i3 = last;
  uint4 r0 = erec[i0], r1 = erec[i1], r2 = erec[i2], r3 = erec[i3];

  for (int j = beg; j < end; j += 8) {
    uint4 c0 = r0, c1 = r1, c2 = r2, c3 = r3;
    i0 = j + 8 + half;  if (i0 > last) i0 = last;
    i1 = j + 10 + half; if (i1 > last) i1 = last;
    i2 = j + 12 + half; if (i2 > last) i2 = last;
    i3 = j + 14 + half; if (i3 > last) i3 = last;
    r0 = erec[i0]; r1 = erec[i1]; r2 = erec[i2]; r3 = erec[i3];

    uint4 h0 = *reinterpret_cast<const uint4*>(Hb + ((c0.x << 9) | off_lane));
    uint4 h1 = *reinterpret_cast<const uint4*>(Hb + ((c1.x << 9) | off_lane));
    uint4 h2 = *reinterpret_cast<const uint4*>(Hb + ((c2.x << 9) | off_lane));
    uint4 h3 = *reinterpret_cast<const uint4*>(Hb + ((c3.x << 9) | off_lane));

    accum_edge(c0, h0, (j + half) < end, acc, den);
    accum_edge(c1, h1, (j + 2 + half) < end, acc, den);
    accum_edge(c2, h2, (j + 4 + half) < end, acc, den);
    accum_edge(c3, h3, (j + 6 + half) < end, acc, den);
  }

#pragma unroll
  for (int k = 0; k < 8; ++k) acc[k] += __shfl_xor(acc[k], 32, 64);
#pragma unroll
  for (int k = 0; k < 4; ++k) den[k] += __shfl_xor(den[k], 32, 64);

  if (lane < 32) {
    float i0v = 1.f / (den[0] + 1e-30f);
    float i1v = 1.f / (den[1] + 1e-30f);
    float i2v = 1.f / (den[2] + 1e-30f);
    float i3v = 1.f / (den[3] + 1e-30f);
    float2 b2 = *reinterpret_cast<const float2*>(bias + 2 * lane);
    float rA = 0.25f * (acc[0] * i0v + acc[1] * i1v + acc[2] * i2v + acc[3] * i3v) + b2.x;
    float rB = 0.25f * (acc[4] * i0v + acc[5] * i1v + acc[6] * i2v + acc[7] * i3v) + b2.y;
    *reinterpret_cast<float2*>(out + (size_t)n * CH + 2 * lane) = make_float2(rA, rB);
  }
}

extern "C" void kernel_launch(void* const* d_in, const int* in_sizes, int n_in,
                              void* d_out, int out_size, void* d_ws, size_t ws_size,
                              hipStream_t stream) {
  const float* x       = (const float*)d_in[0];
  const int*   eidx    = (const int*)d_in[1];
  const float* W       = (const float*)d_in[2];
  const float* att_src = (const float*)d_in[3];
  const float* att_dst = (const float*)d_in[4];
  const float* bias    = (const float*)d_in[5];
  float* out = (float*)d_out;

  uint2* Hmp    = (uint2*)d_ws;                               // N*64 uint2 (51.2MB)
  uint4* erec   = (uint4*)(Hmp + (size_t)N_NODES * 64);       // TOT uint4 (27.2MB)
  float* as_buf = (float*)(erec + (size_t)TOT + 16);          // N*4
  float* ad_buf = as_buf + (size_t)N_NODES * NHEAD;           // N*4
  uint4* Wt_arr = (uint4*)(ad_buf + (size_t)N_NODES * NHEAD); // 8192 uint4 (128KB)
  int*   deg    = (int*)(Wt_arr + 8192);                      // N (reused as cursor)
  int*   rp     = deg + N_NODES;                              // N+1
  int*   bsum   = rp + N_NODES + 1;                           // 128

  const int* esrc = eidx;
  const int* edst = eidx + N_EDGES;

  conv_w<<<32, 256, 0, stream>>>(W, Wt_arr, deg);  // also zeroes deg

  // grid-mix: 391 deg-count blocks first, 1563 GEMM blocks (R15-measured best order)
  dim3 ggrid(DEG_BLOCKS + NGEMM);
  gemm_mfma<<<ggrid, 256, 0, stream>>>(x, Wt_arr, att_src, att_dst, Hmp, as_buf, ad_buf,
                                       edst, deg, N_NODES);

  scan1<<<NBLK1, 256, 0, stream>>>(deg, rp, bsum);
  scan23<<<(N_NODES + 255) / 256, 256, 0, stream>>>(rp, bsum, deg /*cursor*/);
  scatter_edges<<<(TOT + 255) / 256, 256, 0, stream>>>(esrc, edst, as_buf, ad_buf,
                                                       deg /*cursor*/, erec);

  aggregate<<<(N_NODES + 3) / 4, 256, 0, stream>>>(rp, erec, Hmp, bias, out);
}